// Round 3
// baseline (455.817 us; speedup 1.0000x reference)
//
#include <hip/hip_runtime.h>
#include <hip/hip_bf16.h>

#define B_ROWS 8192
#define DIM 256
#define C_CLS 5994
#define C_PAD 6016
#define N_CHUNK 188   // C_PAD / 32
#define N_SPLIT 16
#define H_HALF 4096
#define SCALE_F 30.0f
#define MAXL 30.0f

typedef _Float16 half8 __attribute__((ext_vector_type(8)));
typedef _Float16 half4 __attribute__((ext_vector_type(4)));
typedef float f32x16 __attribute__((ext_vector_type(16)));

// ---------------- prep: row norms + f16 normalized copies ----------------
__global__ void k_prep(const float* __restrict__ emb, const float* __restrict__ W,
                       _Float16* __restrict__ en, _Float16* __restrict__ wn,
                       float* __restrict__ rne, float* __restrict__ rnw) {
  int r = blockIdx.x;
  int lane = threadIdx.x;            // 64 threads
  const float* src; _Float16* dst; float* rn; int row;
  if (r < B_ROWS) { src = emb; dst = en; rn = rne; row = r; }
  else {
    row = r - B_ROWS;
    if (row >= C_CLS) {              // pad rows of wn: zeros
      half4 z = {};
      *(half4*)(wn + row*DIM + lane*4) = z;
      return;
    }
    src = W; dst = wn; rn = rnw;
  }
  float4 v = *(const float4*)(src + row*DIM + lane*4);
  float ss = v.x*v.x + v.y*v.y + v.z*v.z + v.w*v.w;
  #pragma unroll
  for (int off=1; off<64; off<<=1) ss += __shfl_xor(ss, off);
  float s = 1.0f/(sqrtf(ss) + 1e-12f);
  if (lane==0) rn[row] = s;
  half4 h;
  h[0]=(_Float16)(v.x*s); h[1]=(_Float16)(v.y*s);
  h[2]=(_Float16)(v.z*s); h[3]=(_Float16)(v.w*s);
  *(half4*)(dst + row*DIM + lane*4) = h;
}

// ---------------- main fused GEMM + online softmax-stats ----------------
// grid = 32 row-panels x 16 col-splits; block = 256 (4 waves x 64 rows each)
__global__ __launch_bounds__(256, 2)
void k_logits(const _Float16* __restrict__ en, const _Float16* __restrict__ wn,
              float* __restrict__ psum, unsigned* __restrict__ pkey) {
  const int split = blockIdx.x & (N_SPLIT-1);
  const int panel = blockIdx.x / N_SPLIT;
  const int wid  = threadIdx.x >> 6;
  const int lane = threadIdx.x & 63;
  const int l31  = lane & 31;
  const int lh   = lane >> 5;
  const int rowbase = panel*256 + wid*64;

  // A fragments: 2 row-tiles of 32, all K in registers (128 VGPR)
  half8 a0[16], a1[16];
  #pragma unroll
  for (int k=0;k<16;k++) {
    a0[k] = *(const half8*)(en + (rowbase +      l31)*DIM + k*16 + lh*8);
    a1[k] = *(const half8*)(en + (rowbase + 32 + l31)*DIM + k*16 + lh*8);
  }
  float ssum[32];
  unsigned kmax[32];
  #pragma unroll
  for (int t=0;t<32;t++){ ssum[t]=0.f; kmax[t]=0u; }

  for (int c = split; c < N_CHUNK; c += N_SPLIT) {
    const int col0 = c*32;
    f32x16 acc0 = {}, acc1 = {};
    const _Float16* bp = wn + (col0 + l31)*DIM + lh*8;
    #pragma unroll
    for (int k=0;k<16;k++) {
      half8 b = *(const half8*)(bp + k*16);
      acc0 = __builtin_amdgcn_mfma_f32_32x32x16_f16(a0[k], b, acc0, 0,0,0);
      acc1 = __builtin_amdgcn_mfma_f32_32x32x16_f16(a1[k], b, acc1, 0,0,0);
    }
    const int col = col0 + l31;
    const unsigned colu = (unsigned)col;
    if (col0 + 32 <= C_CLS) {        // full chunk, no masking
      #pragma unroll
      for (int r=0;r<16;r++) {
        { float x = SCALE_F*acc0[r];
          ssum[r] += __expf(x - MAXL);
          unsigned u = __float_as_uint(x);
          u ^= ((unsigned)((int)u >> 31)) | 0x80000000u;
          unsigned key = (u & 0xFFFFE000u) | colu;
          if (key > kmax[r]) kmax[r] = key; }
        { float x = SCALE_F*acc1[r];
          ssum[16+r] += __expf(x - MAXL);
          unsigned u = __float_as_uint(x);
          u ^= ((unsigned)((int)u >> 31)) | 0x80000000u;
          unsigned key = (u & 0xFFFFE000u) | colu;
          if (key > kmax[16+r]) kmax[16+r] = key; }
      }
    } else {                          // ragged last chunk
      const bool valid = col < C_CLS;
      #pragma unroll
      for (int r=0;r<16;r++) {
        { float x = SCALE_F*acc0[r];
          float e = valid ? __expf(x - MAXL) : 0.f;
          ssum[r] += e;
          unsigned u = __float_as_uint(x);
          u ^= ((unsigned)((int)u >> 31)) | 0x80000000u;
          unsigned key = valid ? ((u & 0xFFFFE000u) | colu) : 0u;
          if (key > kmax[r]) kmax[r] = key; }
        { float x = SCALE_F*acc1[r];
          float e = valid ? __expf(x - MAXL) : 0.f;
          ssum[16+r] += e;
          unsigned u = __float_as_uint(x);
          u ^= ((unsigned)((int)u >> 31)) | 0x80000000u;
          unsigned key = valid ? ((u & 0xFFFFE000u) | colu) : 0u;
          if (key > kmax[16+r]) kmax[16+r] = key; }
      }
    }
  }
  // reduce across the 32 lanes (cols) of each half
  #pragma unroll
  for (int off=1; off<32; off<<=1) {
    #pragma unroll
    for (int t=0;t<32;t++) {
      ssum[t] += __shfl_xor(ssum[t], off);
      unsigned o = __shfl_xor(kmax[t], off);
      if (o > kmax[t]) kmax[t] = o;
    }
  }
  if (l31 == 0) {
    #pragma unroll
    for (int s=0;s<2;s++) {
      #pragma unroll
      for (int r=0;r<16;r++) {
        int row = rowbase + s*32 + (r&3) + 8*(r>>2) + 4*lh;
        psum[split*B_ROWS + row] = ssum[s*16+r];
        pkey[split*B_ROWS + row] = kmax[s*16+r];
      }
    }
  }
}

// ---------------- das: contrastive pair distances (f32, from raw emb) ----
__global__ void k_das(const float* __restrict__ emb, const int* __restrict__ y_d,
                      float* __restrict__ accum) {
  __shared__ float sp4[4], sn4[4];
  const int i = blockIdx.x;
  const int t = threadIdx.x;          // 256 threads, one per d
  const int j = (i+1) & (H_HALF-1);
  const int di = y_d[i], dj = y_d[j], dih = y_d[i + H_HALF];
  float mi = (di==0)  ? emb[i*DIM + t] : 0.f;
  float mj = (dj==0)  ? emb[j*DIM + t] : 0.f;
  float ti = (dih!=0) ? emb[(i+H_HALF)*DIM + t]
                      : ((di!=0) ? emb[i*DIM + t] : 0.f);
  float p = mi - mj, n = mi - ti;
  float sp = p*p, sn = n*n;
  #pragma unroll
  for (int off=1; off<64; off<<=1) { sp += __shfl_xor(sp, off); sn += __shfl_xor(sn, off); }
  if ((t & 63) == 0) { sp4[t>>6] = sp; sn4[t>>6] = sn; }
  __syncthreads();
  if (t == 0) {
    float spt = sp4[0]+sp4[1]+sp4[2]+sp4[3];
    float snt = sn4[0]+sn4[1]+sn4[2]+sn4[3];
    float dp = sqrtf(spt), dn = sqrtf(snt);
    float m = fmaxf(2.0f - dp, 0.f);
    atomicAdd(&accum[2], m*m + dn*dn);
    atomicAdd(&accum[3], dp + dn);
  }
}

// ---------------- merge: per-row exact y-logit + combine partials --------
__global__ void k_merge(const float* __restrict__ emb, const float* __restrict__ W,
                        const int* __restrict__ y,
                        const float* __restrict__ rne, const float* __restrict__ rnw,
                        const float* __restrict__ psum, const unsigned* __restrict__ pkey,
                        float* __restrict__ accum) {
  const int wid = threadIdx.x >> 6, lane = threadIdx.x & 63;
  const int row = blockIdx.x*4 + wid;
  const int yc = y[row];
  float4 e = *(const float4*)(emb + row*DIM + lane*4);
  float4 w = *(const float4*)(W + yc*DIM + lane*4);
  float d = e.x*w.x + e.y*w.y + e.z*w.z + e.w*w.w;
  #pragma unroll
  for (int off=1; off<64; off<<=1) d += __shfl_xor(d, off);
  if (lane == 0) {
    float ly = SCALE_F * d * rne[row] * rnw[yc];
    float S = 0.f; unsigned km = 0u;
    #pragma unroll
    for (int s=0;s<N_SPLIT;s++) {
      S += psum[s*B_ROWS + row];
      unsigned k = pkey[s*B_ROWS + row];
      if (k > km) km = k;
    }
    float loss = MAXL + logf(S) - ly;
    float corr = ((km & 0x1FFFu) == (unsigned)yc) ? 1.f : 0.f;
    atomicAdd(&accum[0], loss);
    atomicAdd(&accum[1], corr);
  }
}

// ---------------- finalize: f32 outputs (reference returns float32) ------
__global__ void k_fin(const float* __restrict__ accum, float* __restrict__ out) {
  if (threadIdx.x == 0) {
    out[0] = accum[0] * (1.0f/B_ROWS);  // loss_c
    out[1] = accum[2] * (1.0f/B_ROWS);  // das_loss
    out[2] = accum[1] * (1.0f/B_ROWS);  // acc
    out[3] = accum[3] * (1.0f/B_ROWS);  // das_dist_mean
  }
}

extern "C" void kernel_launch(void* const* d_in, const int* in_sizes, int n_in,
                              void* d_out, int out_size, void* d_ws, size_t ws_size,
                              hipStream_t stream) {
  const float* emb = (const float*)d_in[0];
  const float* W   = (const float*)d_in[1];
  const int*   y   = (const int*)d_in[2];
  const int*   y_d = (const int*)d_in[3];

  char* ws = (char*)d_ws;
  const size_t EN_OFF   = 0;                                 // 8192*256*2  = 4,194,304
  const size_t WN_OFF   = EN_OFF  + (size_t)B_ROWS*DIM*2;    // 6016*256*2  = 3,080,192
  const size_t RNE_OFF  = WN_OFF  + (size_t)C_PAD*DIM*2;     // 32,768
  const size_t RNW_OFF  = RNE_OFF + (size_t)B_ROWS*4;        // 24,064 (padded)
  const size_t PSUM_OFF = RNW_OFF + 24064;                   // 16*8192*4 = 524,288
  const size_t PKEY_OFF = PSUM_OFF + (size_t)N_SPLIT*B_ROWS*4;
  const size_t ACC_OFF  = PKEY_OFF + (size_t)N_SPLIT*B_ROWS*4;

  _Float16* en  = (_Float16*)(ws + EN_OFF);
  _Float16* wn  = (_Float16*)(ws + WN_OFF);
  float*    rne = (float*)(ws + RNE_OFF);
  float*    rnw = (float*)(ws + RNW_OFF);
  float*    psum = (float*)(ws + PSUM_OFF);
  unsigned* pkey = (unsigned*)(ws + PKEY_OFF);
  float*    accum = (float*)(ws + ACC_OFF);

  hipMemsetAsync(accum, 0, 4*sizeof(float), stream);

  k_prep<<<B_ROWS + C_PAD, 64, 0, stream>>>(emb, W, en, wn, rne, rnw);
  k_logits<<<32*N_SPLIT, 256, 0, stream>>>(en, wn, psum, pkey);
  k_das<<<H_HALF, 256, 0, stream>>>(emb, y_d, accum);
  k_merge<<<B_ROWS/4, 256, 0, stream>>>(emb, W, y, rne, rnw, psum, pkey, accum);
  k_fin<<<1, 64, 0, stream>>>(accum, (float*)d_out);
}

// Round 4
// 174.888 us; speedup vs baseline: 2.6063x; 2.6063x over previous
//
#include <hip/hip_runtime.h>
#include <hip/hip_bf16.h>

#define B_ROWS 8192
#define DIM 256
#define C_CLS 5994
#define C_PAD 6016
#define N_CHUNK 188   // C_PAD / 32
#define N_SPLIT 16
#define H_HALF 4096
#define SCALE_F 30.0f
#define MAXL 30.0f

typedef _Float16 half8 __attribute__((ext_vector_type(8)));
typedef _Float16 half4 __attribute__((ext_vector_type(4)));
typedef float f32x16 __attribute__((ext_vector_type(16)));

// ---------------- prep: row norms + f16 normalized copies ----------------
__global__ void k_prep(const float* __restrict__ emb, const float* __restrict__ W,
                       _Float16* __restrict__ en, _Float16* __restrict__ wn,
                       float* __restrict__ rne, float* __restrict__ rnw) {
  int r = blockIdx.x;
  int lane = threadIdx.x;            // 64 threads
  const float* src; _Float16* dst; float* rn; int row;
  if (r < B_ROWS) { src = emb; dst = en; rn = rne; row = r; }
  else {
    row = r - B_ROWS;
    if (row >= C_CLS) {              // pad rows of wn: zeros
      half4 z = {};
      *(half4*)(wn + row*DIM + lane*4) = z;
      return;
    }
    src = W; dst = wn; rn = rnw;
  }
  float4 v = *(const float4*)(src + row*DIM + lane*4);
  float ss = v.x*v.x + v.y*v.y + v.z*v.z + v.w*v.w;
  #pragma unroll
  for (int off=1; off<64; off<<=1) ss += __shfl_xor(ss, off);
  float s = 1.0f/(sqrtf(ss) + 1e-12f);
  if (lane==0) rn[row] = s;
  half4 h;
  h[0]=(_Float16)(v.x*s); h[1]=(_Float16)(v.y*s);
  h[2]=(_Float16)(v.z*s); h[3]=(_Float16)(v.w*s);
  *(half4*)(dst + row*DIM + lane*4) = h;
}

// ---------------- main fused GEMM + online softmax-stats ----------------
// grid = 32 row-panels x 16 col-splits; block = 256 (4 waves x 64 rows each)
__global__ __launch_bounds__(256, 2)
void k_logits(const _Float16* __restrict__ en, const _Float16* __restrict__ wn,
              float* __restrict__ psum, unsigned* __restrict__ pkey) {
  const int split = blockIdx.x & (N_SPLIT-1);
  const int panel = blockIdx.x / N_SPLIT;
  const int wid  = threadIdx.x >> 6;
  const int lane = threadIdx.x & 63;
  const int l31  = lane & 31;
  const int lh   = lane >> 5;
  const int rowbase = panel*256 + wid*64;

  // A fragments: 2 row-tiles of 32, all K in registers (128 VGPR)
  half8 a0[16], a1[16];
  #pragma unroll
  for (int k=0;k<16;k++) {
    a0[k] = *(const half8*)(en + (rowbase +      l31)*DIM + k*16 + lh*8);
    a1[k] = *(const half8*)(en + (rowbase + 32 + l31)*DIM + k*16 + lh*8);
  }
  float ssum[32];
  unsigned kmax[32];
  #pragma unroll
  for (int t=0;t<32;t++){ ssum[t]=0.f; kmax[t]=0u; }

  for (int c = split; c < N_CHUNK; c += N_SPLIT) {
    const int col0 = c*32;
    f32x16 acc0 = {}, acc1 = {};
    const _Float16* bp = wn + (col0 + l31)*DIM + lh*8;
    #pragma unroll
    for (int k=0;k<16;k++) {
      half8 b = *(const half8*)(bp + k*16);
      acc0 = __builtin_amdgcn_mfma_f32_32x32x16_f16(a0[k], b, acc0, 0,0,0);
      acc1 = __builtin_amdgcn_mfma_f32_32x32x16_f16(a1[k], b, acc1, 0,0,0);
    }
    const int col = col0 + l31;
    const unsigned colu = (unsigned)col;
    if (col0 + 32 <= C_CLS) {        // full chunk, no masking
      #pragma unroll
      for (int r=0;r<16;r++) {
        { float x = SCALE_F*acc0[r];
          ssum[r] += __expf(x - MAXL);
          unsigned u = __float_as_uint(x);
          u ^= ((unsigned)((int)u >> 31)) | 0x80000000u;
          unsigned key = (u & 0xFFFFE000u) | colu;
          if (key > kmax[r]) kmax[r] = key; }
        { float x = SCALE_F*acc1[r];
          ssum[16+r] += __expf(x - MAXL);
          unsigned u = __float_as_uint(x);
          u ^= ((unsigned)((int)u >> 31)) | 0x80000000u;
          unsigned key = (u & 0xFFFFE000u) | colu;
          if (key > kmax[16+r]) kmax[16+r] = key; }
      }
    } else {                          // ragged last chunk
      const bool valid = col < C_CLS;
      #pragma unroll
      for (int r=0;r<16;r++) {
        { float x = SCALE_F*acc0[r];
          float e = valid ? __expf(x - MAXL) : 0.f;
          ssum[r] += e;
          unsigned u = __float_as_uint(x);
          u ^= ((unsigned)((int)u >> 31)) | 0x80000000u;
          unsigned key = valid ? ((u & 0xFFFFE000u) | colu) : 0u;
          if (key > kmax[r]) kmax[r] = key; }
        { float x = SCALE_F*acc1[r];
          float e = valid ? __expf(x - MAXL) : 0.f;
          ssum[16+r] += e;
          unsigned u = __float_as_uint(x);
          u ^= ((unsigned)((int)u >> 31)) | 0x80000000u;
          unsigned key = valid ? ((u & 0xFFFFE000u) | colu) : 0u;
          if (key > kmax[16+r]) kmax[16+r] = key; }
      }
    }
  }
  // reduce across the 32 lanes (cols) of each half
  #pragma unroll
  for (int off=1; off<32; off<<=1) {
    #pragma unroll
    for (int t=0;t<32;t++) {
      ssum[t] += __shfl_xor(ssum[t], off);
      unsigned o = __shfl_xor(kmax[t], off);
      if (o > kmax[t]) kmax[t] = o;
    }
  }
  if (l31 == 0) {
    #pragma unroll
    for (int s=0;s<2;s++) {
      #pragma unroll
      for (int r=0;r<16;r++) {
        int row = rowbase + s*32 + (r&3) + 8*(r>>2) + 4*lh;
        psum[split*B_ROWS + row] = ssum[s*16+r];
        pkey[split*B_ROWS + row] = kmax[s*16+r];
      }
    }
  }
}

// ---------------- das: contrastive pair distances (f32, from raw emb) ----
// one WAVE per pair i, grid-stride; per-block LDS reduce -> 1 atomic pair/block
__global__ __launch_bounds__(256)
void k_das(const float* __restrict__ emb, const int* __restrict__ y_d,
           float* __restrict__ accum) {
  __shared__ float sl[4], sc[4];
  const int wid = threadIdx.x >> 6, lane = threadIdx.x & 63;
  float a2 = 0.f, a3 = 0.f;
  for (int i = blockIdx.x*4 + wid; i < H_HALF; i += gridDim.x*4) {
    const int j = (i+1) & (H_HALF-1);
    const int di = y_d[i], dj = y_d[j], dih = y_d[i + H_HALF];
    float4 z = {0.f,0.f,0.f,0.f};
    float4 mi = (di==0)  ? *(const float4*)(emb + (size_t)i*DIM + lane*4) : z;
    float4 mj = (dj==0)  ? *(const float4*)(emb + (size_t)j*DIM + lane*4) : z;
    float4 ti = (dih!=0) ? *(const float4*)(emb + (size_t)(i+H_HALF)*DIM + lane*4)
                         : ((di!=0) ? *(const float4*)(emb + (size_t)i*DIM + lane*4) : z);
    float px = mi.x-mj.x, py = mi.y-mj.y, pz = mi.z-mj.z, pw = mi.w-mj.w;
    float nx = mi.x-ti.x, ny = mi.y-ti.y, nz = mi.z-ti.z, nw = mi.w-ti.w;
    float sp = px*px+py*py+pz*pz+pw*pw;
    float sn = nx*nx+ny*ny+nz*nz+nw*nw;
    #pragma unroll
    for (int off=1; off<64; off<<=1) { sp += __shfl_xor(sp, off); sn += __shfl_xor(sn, off); }
    if (lane == 0) {
      float dp = sqrtf(sp), dn = sqrtf(sn);
      float m = fmaxf(2.0f - dp, 0.f);
      a2 += m*m + dn*dn;
      a3 += dp + dn;
    }
  }
  if (lane == 0) { sl[wid] = a2; sc[wid] = a3; }
  __syncthreads();
  if (threadIdx.x == 0) {
    atomicAdd(&accum[2], sl[0]+sl[1]+sl[2]+sl[3]);
    atomicAdd(&accum[3], sc[0]+sc[1]+sc[2]+sc[3]);
  }
}

// ---------------- merge: per-row exact y-logit + combine partials --------
// one WAVE per row, grid-stride; per-block LDS reduce -> 1 atomic pair/block
__global__ __launch_bounds__(256)
void k_merge(const float* __restrict__ emb, const float* __restrict__ W,
             const int* __restrict__ y,
             const float* __restrict__ rne, const float* __restrict__ rnw,
             const float* __restrict__ psum, const unsigned* __restrict__ pkey,
             float* __restrict__ accum) {
  __shared__ float sl[4], sc[4];
  const int wid = threadIdx.x >> 6, lane = threadIdx.x & 63;
  float lacc = 0.f, cacc = 0.f;
  for (int row = blockIdx.x*4 + wid; row < B_ROWS; row += gridDim.x*4) {
    const int yc = y[row];
    float4 e = *(const float4*)(emb + (size_t)row*DIM + lane*4);
    float4 w = *(const float4*)(W + (size_t)yc*DIM + lane*4);
    float d = e.x*w.x + e.y*w.y + e.z*w.z + e.w*w.w;
    #pragma unroll
    for (int off=1; off<64; off<<=1) d += __shfl_xor(d, off);
    // distribute the 16 partial loads across lanes 0..15
    float S = 0.f; unsigned km = 0u;
    if (lane < N_SPLIT) {
      S = psum[lane*B_ROWS + row];
      km = pkey[lane*B_ROWS + row];
    }
    #pragma unroll
    for (int off=1; off<16; off<<=1) {
      S += __shfl_xor(S, off);
      unsigned o = __shfl_xor(km, off);
      if (o > km) km = o;
    }
    if (lane == 0) {
      float ly = SCALE_F * d * rne[row] * rnw[yc];
      lacc += MAXL + logf(S) - ly;
      cacc += ((km & 0x1FFFu) == (unsigned)yc) ? 1.f : 0.f;
    }
  }
  if (lane == 0) { sl[wid] = lacc; sc[wid] = cacc; }
  __syncthreads();
  if (threadIdx.x == 0) {
    atomicAdd(&accum[0], sl[0]+sl[1]+sl[2]+sl[3]);
    atomicAdd(&accum[1], sc[0]+sc[1]+sc[2]+sc[3]);
  }
}

// ---------------- finalize: f32 outputs (reference returns float32) ------
__global__ void k_fin(const float* __restrict__ accum, float* __restrict__ out) {
  if (threadIdx.x == 0) {
    out[0] = accum[0] * (1.0f/B_ROWS);  // loss_c
    out[1] = accum[2] * (1.0f/B_ROWS);  // das_loss
    out[2] = accum[1] * (1.0f/B_ROWS);  // acc
    out[3] = accum[3] * (1.0f/B_ROWS);  // das_dist_mean
  }
}

extern "C" void kernel_launch(void* const* d_in, const int* in_sizes, int n_in,
                              void* d_out, int out_size, void* d_ws, size_t ws_size,
                              hipStream_t stream) {
  const float* emb = (const float*)d_in[0];
  const float* W   = (const float*)d_in[1];
  const int*   y   = (const int*)d_in[2];
  const int*   y_d = (const int*)d_in[3];

  char* ws = (char*)d_ws;
  const size_t EN_OFF   = 0;                                 // 8192*256*2  = 4,194,304
  const size_t WN_OFF   = EN_OFF  + (size_t)B_ROWS*DIM*2;    // 6016*256*2  = 3,080,192
  const size_t RNE_OFF  = WN_OFF  + (size_t)C_PAD*DIM*2;     // 32,768
  const size_t RNW_OFF  = RNE_OFF + (size_t)B_ROWS*4;        // 24,064 (padded)
  const size_t PSUM_OFF = RNW_OFF + 24064;                   // 16*8192*4 = 524,288
  const size_t PKEY_OFF = PSUM_OFF + (size_t)N_SPLIT*B_ROWS*4;
  const size_t ACC_OFF  = PKEY_OFF + (size_t)N_SPLIT*B_ROWS*4;

  _Float16* en  = (_Float16*)(ws + EN_OFF);
  _Float16* wn  = (_Float16*)(ws + WN_OFF);
  float*    rne = (float*)(ws + RNE_OFF);
  float*    rnw = (float*)(ws + RNW_OFF);
  float*    psum = (float*)(ws + PSUM_OFF);
  unsigned* pkey = (unsigned*)(ws + PKEY_OFF);
  float*    accum = (float*)(ws + ACC_OFF);

  hipMemsetAsync(accum, 0, 4*sizeof(float), stream);

  k_prep<<<B_ROWS + C_PAD, 64, 0, stream>>>(emb, W, en, wn, rne, rnw);
  k_logits<<<32*N_SPLIT, 256, 0, stream>>>(en, wn, psum, pkey);
  k_das<<<128, 256, 0, stream>>>(emb, y_d, accum);
  k_merge<<<128, 256, 0, stream>>>(emb, W, y, rne, rnw, psum, pkey, accum);
  k_fin<<<1, 64, 0, stream>>>(accum, (float*)d_out);
}

// Round 5
// 154.427 us; speedup vs baseline: 2.9517x; 1.1325x over previous
//
#include <hip/hip_runtime.h>
#include <hip/hip_bf16.h>

#define B_ROWS 8192
#define DIM 256
#define C_CLS 5994
#define C_PAD 6016
#define N_CHUNK 188   // C_PAD / 32
#define N_SPLIT 16
#define H_HALF 4096
#define SCALE_F 30.0f
#define MAXL 30.0f

typedef _Float16 half8 __attribute__((ext_vector_type(8)));
typedef _Float16 half4 __attribute__((ext_vector_type(4)));
typedef float f32x16 __attribute__((ext_vector_type(16)));

// ---------------- prep: row norms + f16 normalized copies ----------------
__global__ void k_prep(const float* __restrict__ emb, const float* __restrict__ W,
                       _Float16* __restrict__ en, _Float16* __restrict__ wn,
                       float* __restrict__ rne, float* __restrict__ rnw) {
  int r = blockIdx.x;
  int lane = threadIdx.x;            // 64 threads
  const float* src; _Float16* dst; float* rn; int row;
  if (r < B_ROWS) { src = emb; dst = en; rn = rne; row = r; }
  else {
    row = r - B_ROWS;
    if (row >= C_CLS) {              // pad rows of wn: zeros
      half4 z = {};
      *(half4*)(wn + row*DIM + lane*4) = z;
      return;
    }
    src = W; dst = wn; rn = rnw;
  }
  float4 v = *(const float4*)(src + row*DIM + lane*4);
  float ss = v.x*v.x + v.y*v.y + v.z*v.z + v.w*v.w;
  #pragma unroll
  for (int off=1; off<64; off<<=1) ss += __shfl_xor(ss, off);
  float s = 1.0f/(sqrtf(ss) + 1e-12f);
  if (lane==0) rn[row] = s;
  half4 h;
  h[0]=(_Float16)(v.x*s); h[1]=(_Float16)(v.y*s);
  h[2]=(_Float16)(v.z*s); h[3]=(_Float16)(v.w*s);
  *(half4*)(dst + row*DIM + lane*4) = h;
}

// ---------------- main fused GEMM + online softmax-stats ----------------
// grid = 64 row-panels (128 rows) x 16 col-splits; block = 256 (4 waves x 32 rows)
// Per wave: one 32-row tile => a[16]=64 VGPR, acc=16, stats=32 -> ~140 VGPR, no spill.
__global__ __launch_bounds__(256, 2)
void k_logits(const _Float16* __restrict__ en, const _Float16* __restrict__ wn,
              float* __restrict__ psum, unsigned* __restrict__ pkey) {
  const int split = blockIdx.x & (N_SPLIT-1);
  const int panel = blockIdx.x / N_SPLIT;
  const int wid  = threadIdx.x >> 6;
  const int lane = threadIdx.x & 63;
  const int l31  = lane & 31;
  const int lh   = lane >> 5;
  const int rowbase = panel*128 + wid*32;

  // A fragments: one row-tile of 32, all K in registers (64 VGPR)
  half8 a[16];
  #pragma unroll
  for (int k=0;k<16;k++)
    a[k] = *(const half8*)(en + (size_t)(rowbase + l31)*DIM + k*16 + lh*8);

  float ssum[16];
  unsigned kmax[16];
  #pragma unroll
  for (int t=0;t<16;t++){ ssum[t]=0.f; kmax[t]=0u; }

  for (int c = split; c < N_CHUNK; c += N_SPLIT) {
    const int col0 = c*32;
    f32x16 acc = {};
    const _Float16* bp = wn + (size_t)(col0 + l31)*DIM + lh*8;
    #pragma unroll
    for (int k=0;k<16;k++) {
      half8 b = *(const half8*)(bp + k*16);
      acc = __builtin_amdgcn_mfma_f32_32x32x16_f16(a[k], b, acc, 0,0,0);
    }
    const int col = col0 + l31;
    const unsigned colu = (unsigned)col;
    if (col0 + 32 <= C_CLS) {        // full chunk, no masking
      #pragma unroll
      for (int r=0;r<16;r++) {
        float x = SCALE_F*acc[r];
        ssum[r] += __expf(x - MAXL);
        unsigned u = __float_as_uint(x);
        u ^= ((unsigned)((int)u >> 31)) | 0x80000000u;
        unsigned key = (u & 0xFFFFE000u) | colu;
        if (key > kmax[r]) kmax[r] = key;
      }
    } else {                          // ragged last chunk
      const bool valid = col < C_CLS;
      #pragma unroll
      for (int r=0;r<16;r++) {
        float x = SCALE_F*acc[r];
        float e = valid ? __expf(x - MAXL) : 0.f;
        ssum[r] += e;
        unsigned u = __float_as_uint(x);
        u ^= ((unsigned)((int)u >> 31)) | 0x80000000u;
        unsigned key = valid ? ((u & 0xFFFFE000u) | colu) : 0u;
        if (key > kmax[r]) kmax[r] = key;
      }
    }
  }
  // reduce across the 32 lanes (cols); offsets 1..16 stay within each 32-half
  #pragma unroll
  for (int off=1; off<32; off<<=1) {
    #pragma unroll
    for (int t=0;t<16;t++) {
      ssum[t] += __shfl_xor(ssum[t], off);
      unsigned o = __shfl_xor(kmax[t], off);
      if (o > kmax[t]) kmax[t] = o;
    }
  }
  if (l31 == 0) {
    #pragma unroll
    for (int r=0;r<16;r++) {
      int row = rowbase + (r&3) + 8*(r>>2) + 4*lh;
      psum[split*B_ROWS + row] = ssum[r];
      pkey[split*B_ROWS + row] = kmax[r];
    }
  }
}

// ---------------- das: contrastive pair distances (f32, from raw emb) ----
// one WAVE per pair i, grid-stride; per-block LDS reduce -> 1 atomic pair/block
__global__ __launch_bounds__(256)
void k_das(const float* __restrict__ emb, const int* __restrict__ y_d,
           float* __restrict__ accum) {
  __shared__ float sl[4], sc[4];
  const int wid = threadIdx.x >> 6, lane = threadIdx.x & 63;
  float a2 = 0.f, a3 = 0.f;
  for (int i = blockIdx.x*4 + wid; i < H_HALF; i += gridDim.x*4) {
    const int j = (i+1) & (H_HALF-1);
    const int di = y_d[i], dj = y_d[j], dih = y_d[i + H_HALF];
    float4 z = {0.f,0.f,0.f,0.f};
    float4 mi = (di==0)  ? *(const float4*)(emb + (size_t)i*DIM + lane*4) : z;
    float4 mj = (dj==0)  ? *(const float4*)(emb + (size_t)j*DIM + lane*4) : z;
    float4 ti = (dih!=0) ? *(const float4*)(emb + (size_t)(i+H_HALF)*DIM + lane*4)
                         : ((di!=0) ? *(const float4*)(emb + (size_t)i*DIM + lane*4) : z);
    float px = mi.x-mj.x, py = mi.y-mj.y, pz = mi.z-mj.z, pw = mi.w-mj.w;
    float nx = mi.x-ti.x, ny = mi.y-ti.y, nz = mi.z-ti.z, nw = mi.w-ti.w;
    float sp = px*px+py*py+pz*pz+pw*pw;
    float sn = nx*nx+ny*ny+nz*nz+nw*nw;
    #pragma unroll
    for (int off=1; off<64; off<<=1) { sp += __shfl_xor(sp, off); sn += __shfl_xor(sn, off); }
    if (lane == 0) {
      float dp = sqrtf(sp), dn = sqrtf(sn);
      float m = fmaxf(2.0f - dp, 0.f);
      a2 += m*m + dn*dn;
      a3 += dp + dn;
    }
  }
  if (lane == 0) { sl[wid] = a2; sc[wid] = a3; }
  __syncthreads();
  if (threadIdx.x == 0) {
    atomicAdd(&accum[2], sl[0]+sl[1]+sl[2]+sl[3]);
    atomicAdd(&accum[3], sc[0]+sc[1]+sc[2]+sc[3]);
  }
}

// ---------------- merge: per-row exact y-logit + combine partials --------
// one WAVE per row, grid-stride; per-block LDS reduce -> 1 atomic pair/block
__global__ __launch_bounds__(256)
void k_merge(const float* __restrict__ emb, const float* __restrict__ W,
             const int* __restrict__ y,
             const float* __restrict__ rne, const float* __restrict__ rnw,
             const float* __restrict__ psum, const unsigned* __restrict__ pkey,
             float* __restrict__ accum) {
  __shared__ float sl[4], sc[4];
  const int wid = threadIdx.x >> 6, lane = threadIdx.x & 63;
  float lacc = 0.f, cacc = 0.f;
  for (int row = blockIdx.x*4 + wid; row < B_ROWS; row += gridDim.x*4) {
    const int yc = y[row];
    float4 e = *(const float4*)(emb + (size_t)row*DIM + lane*4);
    float4 w = *(const float4*)(W + (size_t)yc*DIM + lane*4);
    float d = e.x*w.x + e.y*w.y + e.z*w.z + e.w*w.w;
    #pragma unroll
    for (int off=1; off<64; off<<=1) d += __shfl_xor(d, off);
    // distribute the 16 partial loads across lanes 0..15
    float S = 0.f; unsigned km = 0u;
    if (lane < N_SPLIT) {
      S = psum[lane*B_ROWS + row];
      km = pkey[lane*B_ROWS + row];
    }
    #pragma unroll
    for (int off=1; off<16; off<<=1) {
      S += __shfl_xor(S, off);
      unsigned o = __shfl_xor(km, off);
      if (o > km) km = o;
    }
    if (lane == 0) {
      float ly = SCALE_F * d * rne[row] * rnw[yc];
      lacc += MAXL + logf(S) - ly;
      cacc += ((km & 0x1FFFu) == (unsigned)yc) ? 1.f : 0.f;
    }
  }
  if (lane == 0) { sl[wid] = lacc; sc[wid] = cacc; }
  __syncthreads();
  if (threadIdx.x == 0) {
    atomicAdd(&accum[0], sl[0]+sl[1]+sl[2]+sl[3]);
    atomicAdd(&accum[1], sc[0]+sc[1]+sc[2]+sc[3]);
  }
}

// ---------------- finalize: f32 outputs (reference returns float32) ------
__global__ void k_fin(const float* __restrict__ accum, float* __restrict__ out) {
  if (threadIdx.x == 0) {
    out[0] = accum[0] * (1.0f/B_ROWS);  // loss_c
    out[1] = accum[2] * (1.0f/B_ROWS);  // das_loss
    out[2] = accum[1] * (1.0f/B_ROWS);  // acc
    out[3] = accum[3] * (1.0f/B_ROWS);  // das_dist_mean
  }
}

extern "C" void kernel_launch(void* const* d_in, const int* in_sizes, int n_in,
                              void* d_out, int out_size, void* d_ws, size_t ws_size,
                              hipStream_t stream) {
  const float* emb = (const float*)d_in[0];
  const float* W   = (const float*)d_in[1];
  const int*   y   = (const int*)d_in[2];
  const int*   y_d = (const int*)d_in[3];

  char* ws = (char*)d_ws;
  const size_t EN_OFF   = 0;                                 // 8192*256*2  = 4,194,304
  const size_t WN_OFF   = EN_OFF  + (size_t)B_ROWS*DIM*2;    // 6016*256*2  = 3,080,192
  const size_t RNE_OFF  = WN_OFF  + (size_t)C_PAD*DIM*2;     // 32,768
  const size_t RNW_OFF  = RNE_OFF + (size_t)B_ROWS*4;        // 24,064 (padded)
  const size_t PSUM_OFF = RNW_OFF + 24064;                   // 16*8192*4 = 524,288
  const size_t PKEY_OFF = PSUM_OFF + (size_t)N_SPLIT*B_ROWS*4;
  const size_t ACC_OFF  = PKEY_OFF + (size_t)N_SPLIT*B_ROWS*4;

  _Float16* en  = (_Float16*)(ws + EN_OFF);
  _Float16* wn  = (_Float16*)(ws + WN_OFF);
  float*    rne = (float*)(ws + RNE_OFF);
  float*    rnw = (float*)(ws + RNW_OFF);
  float*    psum = (float*)(ws + PSUM_OFF);
  unsigned* pkey = (unsigned*)(ws + PKEY_OFF);
  float*    accum = (float*)(ws + ACC_OFF);

  hipMemsetAsync(accum, 0, 4*sizeof(float), stream);

  k_prep<<<B_ROWS + C_PAD, 64, 0, stream>>>(emb, W, en, wn, rne, rnw);
  k_logits<<<64*N_SPLIT, 256, 0, stream>>>(en, wn, psum, pkey);
  k_das<<<128, 256, 0, stream>>>(emb, y_d, accum);
  k_merge<<<128, 256, 0, stream>>>(emb, W, y, rne, rnw, psum, pkey, accum);
  k_fin<<<1, 64, 0, stream>>>(accum, (float*)d_out);
}

// Round 6
// 103.571 us; speedup vs baseline: 4.4010x; 1.4910x over previous
//
#include <hip/hip_runtime.h>
#include <hip/hip_bf16.h>

#define B_ROWS 8192
#define DIM 256
#define C_CLS 5994
#define N_CHUNK 188       // 6016 / 32
#define NSPL 8
#define H_HALF 4096
#define SCALE_F 30.0f
#define MAXL 30.0f
#define EXPC 43.2808512266689f   // 30*log2(e):  exp(30x-30) = exp2(EXPC*x - EXPC)

typedef _Float16 half8 __attribute__((ext_vector_type(8)));
typedef float f32x16 __attribute__((ext_vector_type(16)));

// ---------------- pack: norms + blocked f16 layouts ----------------------
// Blocked layout per 32-row tile (16 KB): half_off = tile*8192 + k*512 + lh*256 + l31*8 + idx
// (k = d/16, lh = (d%16)/8, idx = d%8). A wave's MFMA fragment load (fixed k)
// is then lane-linear: base + lane*8 -> one contiguous 1 KB global load.
// grid: 256 emb-tiles + 188 W-tiles, block = 256.
__global__ __launch_bounds__(256)
void k_pack(const float* __restrict__ emb, const float* __restrict__ W,
            _Float16* __restrict__ en_blk, _Float16* __restrict__ wn_blk,
            float* __restrict__ rne, float* __restrict__ rnw) {
  __shared__ float ssm[256];
  __shared__ float rnl[32];
  const int b = blockIdx.x;
  const bool isW = b >= (B_ROWS/32);
  const int tile = isW ? b - (B_ROWS/32) : b;
  const int t = threadIdx.x;
  const int l31 = t & 31;
  const int row = tile*32 + l31;
  const float* __restrict__ src = isW ? W : emb;
  const bool rv = (!isW) || (row < C_CLS);

  float v[4][8];
  float ss = 0.f;
  #pragma unroll
  for (int i=0;i<4;i++) {
    const int d0 = ((t>>6) + i*4)*16 + ((t>>5)&1)*8;
    if (rv) {
      float4 x0 = *(const float4*)(src + (size_t)row*DIM + d0);
      float4 x1 = *(const float4*)(src + (size_t)row*DIM + d0 + 4);
      v[i][0]=x0.x; v[i][1]=x0.y; v[i][2]=x0.z; v[i][3]=x0.w;
      v[i][4]=x1.x; v[i][5]=x1.y; v[i][6]=x1.z; v[i][7]=x1.w;
      ss += x0.x*x0.x + x0.y*x0.y + x0.z*x0.z + x0.w*x0.w
          + x1.x*x1.x + x1.y*x1.y + x1.z*x1.z + x1.w*x1.w;
    } else {
      #pragma unroll
      for (int j=0;j<8;j++) v[i][j] = 0.f;
    }
  }
  ssm[t] = ss;
  __syncthreads();
  if (t < 32) {
    float s = 0.f;
    #pragma unroll
    for (int j=0;j<8;j++) s += ssm[t + j*32];
    float rn = 1.0f/(sqrtf(s) + 1e-12f);
    rnl[t] = rn;
    int rw = tile*32 + t;
    if (!isW) rne[rw] = rn;
    else if (rw < C_CLS) rnw[rw] = rn;
  }
  __syncthreads();
  const float rn = rnl[l31];
  _Float16* __restrict__ dst = (isW ? wn_blk : en_blk) + (size_t)tile*8192;
  #pragma unroll
  for (int i=0;i<4;i++) {
    half8 h;
    #pragma unroll
    for (int j=0;j<8;j++) h[j] = (_Float16)(v[i][j]*rn);
    *(half8*)(dst + t*8 + i*2048) = h;   // coalesced 16B stores
  }
}

// ---------------- main fused GEMM + online softmax-stats ----------------
// grid = 64 panels x 8 splits = 512 blocks; block = 256 (4 waves x 32-row tile).
// B chunks (16 KB) double-buffered in LDS; reg-staged (load-early, write-late).
__global__ __launch_bounds__(256, 2)
void k_logits(const _Float16* __restrict__ en_blk, const _Float16* __restrict__ wn_blk,
              float* __restrict__ psum, unsigned* __restrict__ pkey) {
  __shared__ __align__(16) _Float16 lbuf[2][8192];   // 2 x 16 KB
  const int split = blockIdx.x & (NSPL-1);
  const int panel = blockIdx.x / NSPL;
  const int wid  = threadIdx.x >> 6;
  const int lane = threadIdx.x & 63;
  const int l31  = lane & 31;
  const int lh   = lane >> 5;
  const int tile = panel*4 + wid;
  const int tid  = threadIdx.x;

  // A fragments: 16 contiguous 1 KB wave-loads
  half8 a[16];
  const _Float16* ab = en_blk + (size_t)tile*8192 + lane*8;
  #pragma unroll
  for (int k=0;k<16;k++) a[k] = *(const half8*)(ab + k*512);

  float ssum[16]; unsigned kmax[16];
  #pragma unroll
  for (int r=0;r<16;r++){ ssum[r]=0.f; kmax[r]=0u; }

  float4 st[4];
  // prologue: chunk c0 -> lbuf[0]; prefetch c0+NSPL into regs
  {
    const float4* s = (const float4*)(wn_blk + (size_t)split*8192) + tid;
    float4* d = (float4*)(&lbuf[0][0]) + tid;
    d[0]=s[0]; d[256]=s[256]; d[512]=s[512]; d[768]=s[768];
    const int cn = split + NSPL;
    if (cn < N_CHUNK) {
      const float4* s2 = (const float4*)(wn_blk + (size_t)cn*8192) + tid;
      st[0]=s2[0]; st[1]=s2[256]; st[2]=s2[512]; st[3]=s2[768];
    }
  }
  __syncthreads();

  int cur = 0;
  for (int c = split; c < N_CHUNK; c += NSPL) {
    const int cn = c + NSPL;
    if (cn < N_CHUNK) {
      // write prefetched chunk to the other buffer (safe: last read of it was
      // two iterations ago, separated by a barrier), then issue next loads.
      float4* d = (float4*)(&lbuf[cur^1][0]) + tid;
      d[0]=st[0]; d[256]=st[1]; d[512]=st[2]; d[768]=st[3];
      const int cnn = cn + NSPL;
      if (cnn < N_CHUNK) {
        const float4* s = (const float4*)(wn_blk + (size_t)cnn*8192) + tid;
        st[0]=s[0]; st[1]=s[256]; st[2]=s[512]; st[3]=s[768];
      }
    }
    // compute current chunk from LDS
    f32x16 acc = {};
    const _Float16* bb = &lbuf[cur][0] + lane*8;
    #pragma unroll
    for (int k=0;k<16;k++) {
      half8 bvec = *(const half8*)(bb + k*512);   // lane-linear ds_read_b128
      acc = __builtin_amdgcn_mfma_f32_32x32x16_f16(a[k], bvec, acc, 0,0,0);
    }
    const int col = c*32 + l31;
    const unsigned colu = (unsigned)col;
    if (c*32 + 32 <= C_CLS) {          // full chunk
      #pragma unroll
      for (int r=0;r<16;r++) {
        float x = acc[r];              // cosine in [-1,1]
        ssum[r] += exp2f(fmaf(x, EXPC, -EXPC));
        unsigned key = (__float_as_uint(x + 2.0f) & 0xFFFFE000u) | colu;  // x+2>0 -> monotone
        kmax[r] = key > kmax[r] ? key : kmax[r];
      }
    } else {                            // ragged last chunk (c == 187)
      const bool valid = col < C_CLS;
      #pragma unroll
      for (int r=0;r<16;r++) {
        float x = acc[r];
        float e = exp2f(fmaf(x, EXPC, -EXPC));
        unsigned key = (__float_as_uint(x + 2.0f) & 0xFFFFE000u) | colu;
        if (!valid) { e = 0.f; key = 0u; }
        ssum[r] += e;
        kmax[r] = key > kmax[r] ? key : kmax[r];
      }
    }
    __syncthreads();
    cur ^= 1;
  }

  // reduce across the 32 lanes (cols); offsets 1..16 stay within each half
  #pragma unroll
  for (int off=1; off<32; off<<=1) {
    #pragma unroll
    for (int r=0;r<16;r++) {
      ssum[r] += __shfl_xor(ssum[r], off);
      unsigned o = __shfl_xor(kmax[r], off);
      kmax[r] = o > kmax[r] ? o : kmax[r];
    }
  }
  if (l31 == 0) {
    const int rowbase = tile*32;
    #pragma unroll
    for (int r=0;r<16;r++) {
      int row = rowbase + (r&3) + 8*(r>>2) + 4*lh;
      psum[split*B_ROWS + row] = ssum[r];
      pkey[split*B_ROWS + row] = kmax[r];
    }
  }
}

// ---------------- tail: das pairs + merge, one launch --------------------
__global__ __launch_bounds__(256)
void k_tail(const float* __restrict__ emb, const float* __restrict__ W,
            const int* __restrict__ y, const int* __restrict__ y_d,
            const float* __restrict__ rne, const float* __restrict__ rnw,
            const float* __restrict__ psum, const unsigned* __restrict__ pkey,
            float* __restrict__ accum) {
  __shared__ float s0[4], s1[4];
  const int wid = threadIdx.x >> 6, lane = threadIdx.x & 63;
  if (blockIdx.x < 128) {
    // ----- merge: per-row exact y-logit + combine partials -----
    float lacc = 0.f, cacc = 0.f;
    for (int row = blockIdx.x*4 + wid; row < B_ROWS; row += 512) {
      const int yc = y[row];
      float4 e = *(const float4*)(emb + (size_t)row*DIM + lane*4);
      float4 w = *(const float4*)(W + (size_t)yc*DIM + lane*4);
      float d = e.x*w.x + e.y*w.y + e.z*w.z + e.w*w.w;
      #pragma unroll
      for (int off=1; off<64; off<<=1) d += __shfl_xor(d, off);
      float S = 0.f; unsigned km = 0u;
      if (lane < NSPL) {
        S = psum[lane*B_ROWS + row];
        km = pkey[lane*B_ROWS + row];
      }
      #pragma unroll
      for (int off=1; off<NSPL; off<<=1) {
        S += __shfl_xor(S, off);
        unsigned o = __shfl_xor(km, off);
        if (o > km) km = o;
      }
      if (lane == 0) {
        float ly = SCALE_F * d * rne[row] * rnw[yc];
        lacc += MAXL + logf(S) - ly;
        cacc += ((km & 0x1FFFu) == (unsigned)yc) ? 1.f : 0.f;
      }
    }
    if (lane == 0) { s0[wid] = lacc; s1[wid] = cacc; }
    __syncthreads();
    if (threadIdx.x == 0) {
      atomicAdd(&accum[0], s0[0]+s0[1]+s0[2]+s0[3]);
      atomicAdd(&accum[1], s1[0]+s1[1]+s1[2]+s1[3]);
    }
  } else {
    // ----- das: contrastive pair distances (f32, from raw emb) -----
    float a2 = 0.f, a3 = 0.f;
    for (int i = (blockIdx.x-128)*4 + wid; i < H_HALF; i += 256) {
      const int j = (i+1) & (H_HALF-1);
      const int di = y_d[i], dj = y_d[j], dih = y_d[i + H_HALF];
      float4 z = {0.f,0.f,0.f,0.f};
      float4 mi = (di==0)  ? *(const float4*)(emb + (size_t)i*DIM + lane*4) : z;
      float4 mj = (dj==0)  ? *(const float4*)(emb + (size_t)j*DIM + lane*4) : z;
      float4 ti = (dih!=0) ? *(const float4*)(emb + (size_t)(i+H_HALF)*DIM + lane*4)
                           : ((di!=0) ? *(const float4*)(emb + (size_t)i*DIM + lane*4) : z);
      float px = mi.x-mj.x, py = mi.y-mj.y, pz = mi.z-mj.z, pw = mi.w-mj.w;
      float nx = mi.x-ti.x, ny = mi.y-ti.y, nz = mi.z-ti.z, nw = mi.w-ti.w;
      float sp = px*px+py*py+pz*pz+pw*pw;
      float sn = nx*nx+ny*ny+nz*nz+nw*nw;
      #pragma unroll
      for (int off=1; off<64; off<<=1) { sp += __shfl_xor(sp, off); sn += __shfl_xor(sn, off); }
      if (lane == 0) {
        float dp = sqrtf(sp), dn = sqrtf(sn);
        float m = fmaxf(2.0f - dp, 0.f);
        a2 += m*m + dn*dn;
        a3 += dp + dn;
      }
    }
    if (lane == 0) { s0[wid] = a2; s1[wid] = a3; }
    __syncthreads();
    if (threadIdx.x == 0) {
      atomicAdd(&accum[2], s0[0]+s0[1]+s0[2]+s0[3]);
      atomicAdd(&accum[3], s1[0]+s1[1]+s1[2]+s1[3]);
    }
  }
}

// ---------------- finalize: f32 outputs ----------------------------------
__global__ void k_fin(const float* __restrict__ accum, float* __restrict__ out) {
  if (threadIdx.x == 0) {
    out[0] = accum[0] * (1.0f/B_ROWS);  // loss_c
    out[1] = accum[2] * (1.0f/B_ROWS);  // das_loss
    out[2] = accum[1] * (1.0f/B_ROWS);  // acc
    out[3] = accum[3] * (1.0f/B_ROWS);  // das_dist_mean
  }
}

extern "C" void kernel_launch(void* const* d_in, const int* in_sizes, int n_in,
                              void* d_out, int out_size, void* d_ws, size_t ws_size,
                              hipStream_t stream) {
  const float* emb = (const float*)d_in[0];
  const float* W   = (const float*)d_in[1];
  const int*   y   = (const int*)d_in[2];
  const int*   y_d = (const int*)d_in[3];

  char* ws = (char*)d_ws;
  const size_t EN_OFF   = 0;                                  // 256 tiles * 16 KB = 4,194,304
  const size_t WN_OFF   = EN_OFF  + (size_t)256*16384;        // 188 tiles * 16 KB = 3,080,192
  const size_t RNE_OFF  = WN_OFF  + (size_t)N_CHUNK*16384;    // 32,768
  const size_t RNW_OFF  = RNE_OFF + (size_t)B_ROWS*4;         // 24,064 (6016 floats)
  const size_t PSUM_OFF = RNW_OFF + 24064;                    // 8*8192*4 = 262,144
  const size_t PKEY_OFF = PSUM_OFF + (size_t)NSPL*B_ROWS*4;   // 262,144
  const size_t ACC_OFF  = PKEY_OFF + (size_t)NSPL*B_ROWS*4;   // 16

  _Float16* en_blk = (_Float16*)(ws + EN_OFF);
  _Float16* wn_blk = (_Float16*)(ws + WN_OFF);
  float*    rne   = (float*)(ws + RNE_OFF);
  float*    rnw   = (float*)(ws + RNW_OFF);
  float*    psum  = (float*)(ws + PSUM_OFF);
  unsigned* pkey  = (unsigned*)(ws + PKEY_OFF);
  float*    accum = (float*)(ws + ACC_OFF);

  hipMemsetAsync(accum, 0, 4*sizeof(float), stream);

  k_pack<<<B_ROWS/32 + N_CHUNK, 256, 0, stream>>>(emb, W, en_blk, wn_blk, rne, rnw);
  k_logits<<<64*NSPL, 256, 0, stream>>>(en_blk, wn_blk, psum, pkey);
  k_tail<<<192, 256, 0, stream>>>(emb, W, y, y_d, rne, rnw, psum, pkey, accum);
  k_fin<<<1, 64, 0, stream>>>(accum, (float*)d_out);
}

// Round 7
// 83.030 us; speedup vs baseline: 5.4898x; 1.2474x over previous
//
#include <hip/hip_runtime.h>
#include <hip/hip_bf16.h>

#define B_ROWS 8192
#define DIM 256
#define C_CLS 5994
#define N_CHUNK 188       // 6016 / 32
#define NSPL 8
#define H_HALF 4096
#define SCALE_F 30.0f
#define MAXL 30.0f
#define EXPC 43.2808512266689f   // 30*log2(e):  exp(30x-30) = exp2(EXPC*x - EXPC)

typedef _Float16 half8 __attribute__((ext_vector_type(8)));
typedef float f32x16 __attribute__((ext_vector_type(16)));
typedef unsigned long long u64;

// ---------------- pack: norms + blocked f16 layouts ----------------------
// Blocked layout per 32-row tile (16 KB): half_off = tile*8192 + k*512 + lh*256 + l31*8 + idx
// (k = d/16, lh = (d%16)/8, idx = d%8). A wave's MFMA fragment load (fixed k)
// is then lane-linear: base + lane*8 -> one contiguous 1 KB global load.
__global__ __launch_bounds__(256)
void k_pack(const float* __restrict__ emb, const float* __restrict__ W,
            _Float16* __restrict__ en_blk, _Float16* __restrict__ wn_blk,
            float* __restrict__ rne, float* __restrict__ rnw) {
  __shared__ float ssm[256];
  __shared__ float rnl[32];
  const int b = blockIdx.x;
  const bool isW = b >= (B_ROWS/32);
  const int tile = isW ? b - (B_ROWS/32) : b;
  const int t = threadIdx.x;
  const int l31 = t & 31;
  const int row = tile*32 + l31;
  const float* __restrict__ src = isW ? W : emb;
  const bool rv = (!isW) || (row < C_CLS);

  float v[4][8];
  float ss = 0.f;
  #pragma unroll
  for (int i=0;i<4;i++) {
    const int d0 = ((t>>6) + i*4)*16 + ((t>>5)&1)*8;
    if (rv) {
      float4 x0 = *(const float4*)(src + (size_t)row*DIM + d0);
      float4 x1 = *(const float4*)(src + (size_t)row*DIM + d0 + 4);
      v[i][0]=x0.x; v[i][1]=x0.y; v[i][2]=x0.z; v[i][3]=x0.w;
      v[i][4]=x1.x; v[i][5]=x1.y; v[i][6]=x1.z; v[i][7]=x1.w;
      ss += x0.x*x0.x + x0.y*x0.y + x0.z*x0.z + x0.w*x0.w
          + x1.x*x1.x + x1.y*x1.y + x1.z*x1.z + x1.w*x1.w;
    } else {
      #pragma unroll
      for (int j=0;j<8;j++) v[i][j] = 0.f;
    }
  }
  ssm[t] = ss;
  __syncthreads();
  if (t < 32) {
    float s = 0.f;
    #pragma unroll
    for (int j=0;j<8;j++) s += ssm[t + j*32];
    float rn = 1.0f/(sqrtf(s) + 1e-12f);
    rnl[t] = rn;
    int rw = tile*32 + t;
    if (!isW) rne[rw] = rn;
    else if (rw < C_CLS) rnw[rw] = rn;
  }
  __syncthreads();
  const float rn = rnl[l31];
  _Float16* __restrict__ dst = (isW ? wn_blk : en_blk) + (size_t)tile*8192;
  #pragma unroll
  for (int i=0;i<4;i++) {
    half8 h;
    #pragma unroll
    for (int j=0;j<8;j++) h[j] = (_Float16)(v[i][j]*rn);
    *(half8*)(dst + t*8 + i*2048) = h;   // coalesced 16B stores
  }
}

// ---------------- main fused GEMM + online softmax-stats ----------------
// grid = 64 panels x 8 splits = 512 blocks; block = 256 (4 waves x 32-row tile).
// Barrier-free: B streamed from L2/L1 via contiguous 1 KB wave-loads,
// register-double-buffered in two half-chunk buffers (8 loads in flight).
__global__ __launch_bounds__(256, 2)
void k_logits(const _Float16* __restrict__ en_blk, const _Float16* __restrict__ wn_blk,
              float* __restrict__ psum, u64* __restrict__ pkey) {
  const int split = blockIdx.x & (NSPL-1);
  const int panel = blockIdx.x / NSPL;
  const int wid  = threadIdx.x >> 6;
  const int lane = threadIdx.x & 63;
  const int l31  = lane & 31;
  const int lh   = lane >> 5;
  const int tile = panel*4 + wid;

  // A fragments: 16 contiguous 1 KB wave-loads, resident all loop
  half8 a[16];
  const _Float16* ab = en_blk + (size_t)tile*8192 + lane*8;
  #pragma unroll
  for (int k=0;k<16;k++) a[k] = *(const half8*)(ab + k*512);

  float ssum[16], vmax[16]; unsigned cmax[16];
  #pragma unroll
  for (int r=0;r<16;r++){ ssum[r]=0.f; vmax[r]=-2.f; cmax[r]=0u; }

  const _Float16* wb = wn_blk + lane*8;
  half8 b0[8], b1[8];
  {
    const _Float16* p = wb + (size_t)split*8192;
    #pragma unroll
    for (int k=0;k<8;k++) b0[k] = *(const half8*)(p + k*512);
    #pragma unroll
    for (int k=0;k<8;k++) b1[k] = *(const half8*)(p + (k+8)*512);
  }

  for (int c = split; c < N_CHUNK; c += NSPL) {
    const int cn = c + NSPL;
    const _Float16* p = wb + (size_t)cn*8192;
    f32x16 acc = {};
    #pragma unroll
    for (int k=0;k<8;k++)
      acc = __builtin_amdgcn_mfma_f32_32x32x16_f16(a[k], b0[k], acc, 0,0,0);
    if (cn < N_CHUNK) {            // issue next-chunk lo-half loads
      #pragma unroll
      for (int k=0;k<8;k++) b0[k] = *(const half8*)(p + k*512);
    }
    #pragma unroll
    for (int k=0;k<8;k++)
      acc = __builtin_amdgcn_mfma_f32_32x32x16_f16(a[k+8], b1[k], acc, 0,0,0);
    if (cn < N_CHUNK) {            // issue next-chunk hi-half loads
      #pragma unroll
      for (int k=0;k<8;k++) b1[k] = *(const half8*)(p + (k+8)*512);
    }
    // epilogue: pad cols (>=C_CLS) are zero rows -> x=0 -> exp2(-43.3)~1e-13, no mask needed
    const unsigned colu = (unsigned)(c*32 + l31);
    #pragma unroll
    for (int r=0;r<16;r++) {
      float x = acc[r];            // cosine in [-1,1]
      ssum[r] += exp2f(fmaf(x, EXPC, -EXPC));
      if (x > vmax[r]) { vmax[r] = x; cmax[r] = colu; }
    }
  }

  // pack (vmax, col) into a u64 key: larger value wins; on equal value smaller col wins
  u64 key[16];
  #pragma unroll
  for (int r=0;r<16;r++)
    key[r] = ((u64)__float_as_uint(vmax[r] + 2.0f) << 32) | (unsigned)(~cmax[r]);
  #pragma unroll
  for (int off=1; off<32; off<<=1) {
    #pragma unroll
    for (int r=0;r<16;r++) {
      ssum[r] += __shfl_xor(ssum[r], off);
      u64 o = __shfl_xor(key[r], off);
      key[r] = o > key[r] ? o : key[r];
    }
  }
  if (l31 == 0) {
    const int rowbase = tile*32;
    #pragma unroll
    for (int r=0;r<16;r++) {
      int row = rowbase + (r&3) + 8*(r>>2) + 4*lh;
      psum[split*B_ROWS + row] = ssum[r];
      pkey[split*B_ROWS + row] = key[r];
    }
  }
}

// ---------------- tail: das pairs + merge, one launch --------------------
__global__ __launch_bounds__(256)
void k_tail(const float* __restrict__ emb, const float* __restrict__ W,
            const int* __restrict__ y, const int* __restrict__ y_d,
            const float* __restrict__ rne, const float* __restrict__ rnw,
            const float* __restrict__ psum, const u64* __restrict__ pkey,
            float* __restrict__ accum) {
  __shared__ float s0[4], s1[4];
  const int wid = threadIdx.x >> 6, lane = threadIdx.x & 63;
  if (blockIdx.x < 128) {
    // ----- merge: per-row exact y-logit + combine partials -----
    float lacc = 0.f, cacc = 0.f;
    for (int row = blockIdx.x*4 + wid; row < B_ROWS; row += 512) {
      const int yc = y[row];
      float4 e = *(const float4*)(emb + (size_t)row*DIM + lane*4);
      float4 w = *(const float4*)(W + (size_t)yc*DIM + lane*4);
      float d = e.x*w.x + e.y*w.y + e.z*w.z + e.w*w.w;
      #pragma unroll
      for (int off=1; off<64; off<<=1) d += __shfl_xor(d, off);
      float S = 0.f; u64 km = 0;
      if (lane < NSPL) {
        S = psum[lane*B_ROWS + row];
        km = pkey[lane*B_ROWS + row];
      }
      #pragma unroll
      for (int off=1; off<NSPL; off<<=1) {
        S += __shfl_xor(S, off);
        u64 o = __shfl_xor(km, off);
        if (o > km) km = o;
      }
      if (lane == 0) {
        float ly = SCALE_F * d * rne[row] * rnw[yc];
        lacc += MAXL + logf(S) - ly;
        unsigned col = ~(unsigned)km;
        cacc += (col == (unsigned)yc) ? 1.f : 0.f;
      }
    }
    if (lane == 0) { s0[wid] = lacc; s1[wid] = cacc; }
    __syncthreads();
    if (threadIdx.x == 0) {
      atomicAdd(&accum[0], s0[0]+s0[1]+s0[2]+s0[3]);
      atomicAdd(&accum[1], s1[0]+s1[1]+s1[2]+s1[3]);
    }
  } else {
    // ----- das: contrastive pair distances (f32, from raw emb) -----
    float a2 = 0.f, a3 = 0.f;
    for (int i = (blockIdx.x-128)*4 + wid; i < H_HALF; i += 256) {
      const int j = (i+1) & (H_HALF-1);
      const int di = y_d[i], dj = y_d[j], dih = y_d[i + H_HALF];
      float4 z = {0.f,0.f,0.f,0.f};
      float4 mi = (di==0)  ? *(const float4*)(emb + (size_t)i*DIM + lane*4) : z;
      float4 mj = (dj==0)  ? *(const float4*)(emb + (size_t)j*DIM + lane*4) : z;
      float4 ti = (dih!=0) ? *(const float4*)(emb + (size_t)(i+H_HALF)*DIM + lane*4)
                           : ((di!=0) ? *(const float4*)(emb + (size_t)i*DIM + lane*4) : z);
      float px = mi.x-mj.x, py = mi.y-mj.y, pz = mi.z-mj.z, pw = mi.w-mj.w;
      float nx = mi.x-ti.x, ny = mi.y-ti.y, nz = mi.z-ti.z, nw = mi.w-ti.w;
      float sp = px*px+py*py+pz*pz+pw*pw;
      float sn = nx*nx+ny*ny+nz*nz+nw*nw;
      #pragma unroll
      for (int off=1; off<64; off<<=1) { sp += __shfl_xor(sp, off); sn += __shfl_xor(sn, off); }
      if (lane == 0) {
        float dp = sqrtf(sp), dn = sqrtf(sn);
        float m = fmaxf(2.0f - dp, 0.f);
        a2 += m*m + dn*dn;
        a3 += dp + dn;
      }
    }
    if (lane == 0) { s0[wid] = a2; s1[wid] = a3; }
    __syncthreads();
    if (threadIdx.x == 0) {
      atomicAdd(&accum[2], s0[0]+s0[1]+s0[2]+s0[3]);
      atomicAdd(&accum[3], s1[0]+s1[1]+s1[2]+s1[3]);
    }
  }
}

// ---------------- finalize: f32 outputs ----------------------------------
__global__ void k_fin(const float* __restrict__ accum, float* __restrict__ out) {
  if (threadIdx.x == 0) {
    out[0] = accum[0] * (1.0f/B_ROWS);  // loss_c
    out[1] = accum[2] * (1.0f/B_ROWS);  // das_loss
    out[2] = accum[1] * (1.0f/B_ROWS);  // acc
    out[3] = accum[3] * (1.0f/B_ROWS);  // das_dist_mean
  }
}

extern "C" void kernel_launch(void* const* d_in, const int* in_sizes, int n_in,
                              void* d_out, int out_size, void* d_ws, size_t ws_size,
                              hipStream_t stream) {
  const float* emb = (const float*)d_in[0];
  const float* W   = (const float*)d_in[1];
  const int*   y   = (const int*)d_in[2];
  const int*   y_d = (const int*)d_in[3];

  char* ws = (char*)d_ws;
  const size_t EN_OFF   = 0;                                  // 256 tiles * 16 KB = 4,194,304
  const size_t WN_OFF   = EN_OFF  + (size_t)256*16384;        // 188 tiles * 16 KB = 3,080,192
  const size_t RNE_OFF  = WN_OFF  + (size_t)N_CHUNK*16384;    // 32,768
  const size_t RNW_OFF  = RNE_OFF + (size_t)B_ROWS*4;         // 24,064 (6016 floats)
  const size_t PSUM_OFF = RNW_OFF + 24064;                    // 8*8192*4 = 262,144
  const size_t PKEY_OFF = PSUM_OFF + (size_t)NSPL*B_ROWS*4;   // 8*8192*8 = 524,288
  const size_t ACC_OFF  = PKEY_OFF + (size_t)NSPL*B_ROWS*8;   // 16

  _Float16* en_blk = (_Float16*)(ws + EN_OFF);
  _Float16* wn_blk = (_Float16*)(ws + WN_OFF);
  float*    rne   = (float*)(ws + RNE_OFF);
  float*    rnw   = (float*)(ws + RNW_OFF);
  float*    psum  = (float*)(ws + PSUM_OFF);
  u64*      pkey  = (u64*)(ws + PKEY_OFF);
  float*    accum = (float*)(ws + ACC_OFF);

  hipMemsetAsync(accum, 0, 4*sizeof(float), stream);

  k_pack<<<B_ROWS/32 + N_CHUNK, 256, 0, stream>>>(emb, W, en_blk, wn_blk, rne, rnw);
  k_logits<<<64*NSPL, 256, 0, stream>>>(en_blk, wn_blk, psum, pkey);
  k_tail<<<192, 256, 0, stream>>>(emb, W, y, y_d, rne, rnw, psum, pkey, accum);
  k_fin<<<1, 64, 0, stream>>>(accum, (float*)d_out);
}

// Round 8
// 76.366 us; speedup vs baseline: 5.9689x; 1.0873x over previous
//
#include <hip/hip_runtime.h>
#include <hip/hip_bf16.h>

#define B_ROWS 8192
#define DIM 256
#define C_CLS 5994
#define N_CHUNK 188       // 6016 / 32
#define NSPL 8
#define H_HALF 4096
#define SCALE_F 30.0f
#define MAXL 30.0f
#define EXPC 43.2808512266689f   // 30*log2(e):  exp(30x-30) = exp2(EXPC*x - EXPC)

#if defined(__has_builtin)
#if __has_builtin(__builtin_amdgcn_exp2f)
#define EXP2(x) __builtin_amdgcn_exp2f(x)
#endif
#endif
#ifndef EXP2
#define EXP2(x) exp2f(x)
#endif

typedef _Float16 half8 __attribute__((ext_vector_type(8)));
typedef float f32x16 __attribute__((ext_vector_type(16)));

// ---------------- pack: norms + blocked f16 layouts + accum zero ---------
// Blocked layout per 32-row tile (16 KB): half_off = tile*8192 + k*512 + lh*256 + l31*8 + idx
// A wave's MFMA fragment load (fixed k) is lane-linear -> one contiguous 1 KB load.
__global__ __launch_bounds__(256)
void k_pack(const float* __restrict__ emb, const float* __restrict__ W,
            _Float16* __restrict__ en_blk, _Float16* __restrict__ wn_blk,
            float* __restrict__ rne, float* __restrict__ rnw,
            float* __restrict__ accum) {
  __shared__ float ssm[256];
  __shared__ float rnl[32];
  const int b = blockIdx.x;
  const int t = threadIdx.x;
  if (b == 0 && t < 8) accum[t] = 0.f;   // accum[0..3] + counter(+pad), zeroed every call
  const bool isW = b >= (B_ROWS/32);
  const int tile = isW ? b - (B_ROWS/32) : b;
  const int l31 = t & 31;
  const int row = tile*32 + l31;
  const float* __restrict__ src = isW ? W : emb;
  const bool rv = (!isW) || (row < C_CLS);

  float v[4][8];
  float ss = 0.f;
  #pragma unroll
  for (int i=0;i<4;i++) {
    const int d0 = ((t>>6) + i*4)*16 + ((t>>5)&1)*8;
    if (rv) {
      float4 x0 = *(const float4*)(src + (size_t)row*DIM + d0);
      float4 x1 = *(const float4*)(src + (size_t)row*DIM + d0 + 4);
      v[i][0]=x0.x; v[i][1]=x0.y; v[i][2]=x0.z; v[i][3]=x0.w;
      v[i][4]=x1.x; v[i][5]=x1.y; v[i][6]=x1.z; v[i][7]=x1.w;
      ss += x0.x*x0.x + x0.y*x0.y + x0.z*x0.z + x0.w*x0.w
          + x1.x*x1.x + x1.y*x1.y + x1.z*x1.z + x1.w*x1.w;
    } else {
      #pragma unroll
      for (int j=0;j<8;j++) v[i][j] = 0.f;
    }
  }
  ssm[t] = ss;
  __syncthreads();
  if (t < 32) {
    float s = 0.f;
    #pragma unroll
    for (int j=0;j<8;j++) s += ssm[t + j*32];
    float rn = 1.0f/(sqrtf(s) + 1e-12f);
    rnl[t] = rn;
    int rw = tile*32 + t;
    if (!isW) rne[rw] = rn;
    else if (rw < C_CLS) rnw[rw] = rn;
  }
  __syncthreads();
  const float rn = rnl[l31];
  _Float16* __restrict__ dst = (isW ? wn_blk : en_blk) + (size_t)tile*8192;
  #pragma unroll
  for (int i=0;i<4;i++) {
    half8 h;
    #pragma unroll
    for (int j=0;j<8;j++) h[j] = (_Float16)(v[i][j]*rn);
    *(half8*)(dst + t*8 + i*2048) = h;   // coalesced 16B stores
  }
}

// ---------------- main fused GEMM + online softmax-stats ----------------
// grid = 64 panels x 8 splits = 512 blocks; block = 256 (4 waves x 32-row tile).
// Barrier-free; B register-double-buffered; branch-free main loop (peeled tail).
__global__ __launch_bounds__(256, 2)
void k_logits(const _Float16* __restrict__ en_blk, const _Float16* __restrict__ wn_blk,
              float* __restrict__ psum, unsigned* __restrict__ pkey) {
  const int split = blockIdx.x & (NSPL-1);
  const int panel = blockIdx.x / NSPL;
  const int wid  = threadIdx.x >> 6;
  const int lane = threadIdx.x & 63;
  const int l31  = lane & 31;
  const int lh   = lane >> 5;
  const int tile = panel*4 + wid;

  // A fragments: 16 contiguous 1 KB wave-loads, resident all loop
  half8 a[16];
  const _Float16* ab = en_blk + (size_t)tile*8192 + lane*8;
  #pragma unroll
  for (int k=0;k<16;k++) a[k] = *(const half8*)(ab + k*512);

  float ssum[16]; unsigned key[16];
  #pragma unroll
  for (int r=0;r<16;r++){ ssum[r]=0.f; key[r]=0u; }

  const int nit = (N_CHUNK - split + NSPL - 1) / NSPL;   // 24 or 23
  const _Float16* p = wn_blk + (size_t)split*8192 + lane*8;
  const ptrdiff_t STEP = (ptrdiff_t)NSPL*8192;

  half8 b0[8], b1[8];
  #pragma unroll
  for (int k=0;k<8;k++) b0[k] = *(const half8*)(p + k*512);
  #pragma unroll
  for (int k=0;k<8;k++) b1[k] = *(const half8*)(p + (k+8)*512);

  unsigned colu = (unsigned)(split*32 + l31);
  for (int it = 0; it < nit-1; ++it) {
    const _Float16* pn = p + STEP;
    f32x16 acc = {};
    #pragma unroll
    for (int k=0;k<8;k++)
      acc = __builtin_amdgcn_mfma_f32_32x32x16_f16(a[k], b0[k], acc, 0,0,0);
    #pragma unroll
    for (int k=0;k<8;k++) b0[k] = *(const half8*)(pn + k*512);
    #pragma unroll
    for (int k=0;k<8;k++)
      acc = __builtin_amdgcn_mfma_f32_32x32x16_f16(a[k+8], b1[k], acc, 0,0,0);
    #pragma unroll
    for (int k=0;k<8;k++) b1[k] = *(const half8*)(pn + (k+8)*512);
    // epilogue: pad cols are zero rows -> x=0 -> exp2(-43.3)~1e-13, negligible
    #pragma unroll
    for (int r=0;r<16;r++) {
      float x = acc[r];                       // cosine in [-1,1]
      ssum[r] += EXP2(fmaf(x, EXPC, -EXPC));  // single v_exp_f32
      unsigned ky = (__float_as_uint(x + 2.0f) & 0xFFFFE000u) | colu;  // x+2>0: monotone
      key[r] = ky > key[r] ? ky : key[r];
    }
    colu += NSPL*32;
    p = pn;
  }
  { // last chunk, no prefetch
    f32x16 acc = {};
    #pragma unroll
    for (int k=0;k<8;k++)
      acc = __builtin_amdgcn_mfma_f32_32x32x16_f16(a[k], b0[k], acc, 0,0,0);
    #pragma unroll
    for (int k=0;k<8;k++)
      acc = __builtin_amdgcn_mfma_f32_32x32x16_f16(a[k+8], b1[k], acc, 0,0,0);
    #pragma unroll
    for (int r=0;r<16;r++) {
      float x = acc[r];
      ssum[r] += EXP2(fmaf(x, EXPC, -EXPC));
      unsigned ky = (__float_as_uint(x + 2.0f) & 0xFFFFE000u) | colu;
      key[r] = ky > key[r] ? ky : key[r];
    }
  }

  // reduce across the 32 lanes (cols); offsets 1..16 stay within each half
  #pragma unroll
  for (int off=1; off<32; off<<=1) {
    #pragma unroll
    for (int r=0;r<16;r++) {
      ssum[r] += __shfl_xor(ssum[r], off);
      unsigned o = __shfl_xor(key[r], off);
      key[r] = o > key[r] ? o : key[r];
    }
  }
  if (l31 == 0) {
    const int rowbase = tile*32;
    #pragma unroll
    for (int r=0;r<16;r++) {
      int row = rowbase + (r&3) + 8*(r>>2) + 4*lh;
      psum[split*B_ROWS + row] = ssum[r];
      pkey[split*B_ROWS + row] = key[r];
    }
  }
}

// ---------------- tail: das + merge + finalize (completion counter) ------
__global__ __launch_bounds__(256)
void k_tail(const float* __restrict__ emb, const float* __restrict__ W,
            const int* __restrict__ y, const int* __restrict__ y_d,
            const float* __restrict__ rne, const float* __restrict__ rnw,
            const float* __restrict__ psum, const unsigned* __restrict__ pkey,
            float* __restrict__ accum, float* __restrict__ out) {
  __shared__ float s0[4], s1[4];
  const int wid = threadIdx.x >> 6, lane = threadIdx.x & 63;
  if (blockIdx.x < 128) {
    // ----- merge: per-row exact y-logit + combine partials -----
    float lacc = 0.f, cacc = 0.f;
    for (int row = blockIdx.x*4 + wid; row < B_ROWS; row += 512) {
      const int yc = y[row];
      float4 e = *(const float4*)(emb + (size_t)row*DIM + lane*4);
      float4 w = *(const float4*)(W + (size_t)yc*DIM + lane*4);
      float d = e.x*w.x + e.y*w.y + e.z*w.z + e.w*w.w;
      #pragma unroll
      for (int off=1; off<64; off<<=1) d += __shfl_xor(d, off);
      float S = 0.f; unsigned km = 0u;
      if (lane < NSPL) {
        S = psum[lane*B_ROWS + row];
        km = pkey[lane*B_ROWS + row];
      }
      #pragma unroll
      for (int off=1; off<NSPL; off<<=1) {
        S += __shfl_xor(S, off);
        unsigned o = __shfl_xor(km, off);
        if (o > km) km = o;
      }
      if (lane == 0) {
        float ly = SCALE_F * d * rne[row] * rnw[yc];
        lacc += MAXL + logf(S) - ly;
        cacc += ((km & 0x1FFFu) == (unsigned)yc) ? 1.f : 0.f;
      }
    }
    if (lane == 0) { s0[wid] = lacc; s1[wid] = cacc; }
    __syncthreads();
    if (threadIdx.x == 0) {
      atomicAdd(&accum[0], s0[0]+s0[1]+s0[2]+s0[3]);
      atomicAdd(&accum[1], s1[0]+s1[1]+s1[2]+s1[3]);
    }
  } else {
    // ----- das: contrastive pair distances (f32, from raw emb) -----
    float a2 = 0.f, a3 = 0.f;
    for (int i = (blockIdx.x-128)*4 + wid; i < H_HALF; i += 256) {
      const int j = (i+1) & (H_HALF-1);
      const int di = y_d[i], dj = y_d[j], dih = y_d[i + H_HALF];
      float4 z = {0.f,0.f,0.f,0.f};
      float4 mi = (di==0)  ? *(const float4*)(emb + (size_t)i*DIM + lane*4) : z;
      float4 mj = (dj==0)  ? *(const float4*)(emb + (size_t)j*DIM + lane*4) : z;
      float4 ti = (dih!=0) ? *(const float4*)(emb + (size_t)(i+H_HALF)*DIM + lane*4)
                           : ((di!=0) ? *(const float4*)(emb + (size_t)i*DIM + lane*4) : z);
      float px = mi.x-mj.x, py = mi.y-mj.y, pz = mi.z-mj.z, pw = mi.w-mj.w;
      float nx = mi.x-ti.x, ny = mi.y-ti.y, nz = mi.z-ti.z, nw = mi.w-ti.w;
      float sp = px*px+py*py+pz*pz+pw*pw;
      float sn = nx*nx+ny*ny+nz*nz+nw*nw;
      #pragma unroll
      for (int off=1; off<64; off<<=1) { sp += __shfl_xor(sp, off); sn += __shfl_xor(sn, off); }
      if (lane == 0) {
        float dp = sqrtf(sp), dn = sqrtf(sn);
        float m = fmaxf(2.0f - dp, 0.f);
        a2 += m*m + dn*dn;
        a3 += dp + dn;
      }
    }
    if (lane == 0) { s0[wid] = a2; s1[wid] = a3; }
    __syncthreads();
    if (threadIdx.x == 0) {
      atomicAdd(&accum[2], s0[0]+s0[1]+s0[2]+s0[3]);
      atomicAdd(&accum[3], s1[0]+s1[1]+s1[2]+s1[3]);
    }
  }
  // ----- finalize: last block to finish writes the 4 outputs -----
  if (threadIdx.x == 0) {
    __threadfence();                                   // publish accum adds
    unsigned* cnt = (unsigned*)(accum + 4);
    unsigned done = atomicAdd(cnt, 1u);
    if (done == 191u) {                                // last of 192 blocks
      float v0 = atomicAdd(&accum[0], 0.f);            // coherent reads
      float v1 = atomicAdd(&accum[1], 0.f);
      float v2 = atomicAdd(&accum[2], 0.f);
      float v3 = atomicAdd(&accum[3], 0.f);
      out[0] = v0 * (1.0f/B_ROWS);  // loss_c
      out[1] = v2 * (1.0f/B_ROWS);  // das_loss
      out[2] = v1 * (1.0f/B_ROWS);  // acc
      out[3] = v3 * (1.0f/B_ROWS);  // das_dist_mean
    }
  }
}

extern "C" void kernel_launch(void* const* d_in, const int* in_sizes, int n_in,
                              void* d_out, int out_size, void* d_ws, size_t ws_size,
                              hipStream_t stream) {
  const float* emb = (const float*)d_in[0];
  const float* W   = (const float*)d_in[1];
  const int*   y   = (const int*)d_in[2];
  const int*   y_d = (const int*)d_in[3];

  char* ws = (char*)d_ws;
  const size_t EN_OFF   = 0;                                  // 256 tiles * 16 KB = 4,194,304
  const size_t WN_OFF   = EN_OFF  + (size_t)256*16384;        // 188 tiles * 16 KB = 3,080,192
  const size_t RNE_OFF  = WN_OFF  + (size_t)N_CHUNK*16384;    // 32,768
  const size_t RNW_OFF  = RNE_OFF + (size_t)B_ROWS*4;         // 24,064 (6016 floats)
  const size_t PSUM_OFF = RNW_OFF + 24064;                    // 8*8192*4 = 262,144
  const size_t PKEY_OFF = PSUM_OFF + (size_t)NSPL*B_ROWS*4;   // 8*8192*4 = 262,144
  const size_t ACC_OFF  = PKEY_OFF + (size_t)NSPL*B_ROWS*4;   // 32 (4 floats + cnt + pad)

  _Float16* en_blk = (_Float16*)(ws + EN_OFF);
  _Float16* wn_blk = (_Float16*)(ws + WN_OFF);
  float*    rne   = (float*)(ws + RNE_OFF);
  float*    rnw   = (float*)(ws + RNW_OFF);
  float*    psum  = (float*)(ws + PSUM_OFF);
  unsigned* pkey  = (unsigned*)(ws + PKEY_OFF);
  float*    accum = (float*)(ws + ACC_OFF);

  k_pack<<<B_ROWS/32 + N_CHUNK, 256, 0, stream>>>(emb, W, en_blk, wn_blk, rne, rnw, accum);
  k_logits<<<64*NSPL, 256, 0, stream>>>(en_blk, wn_blk, psum, pkey);
  k_tail<<<192, 256, 0, stream>>>(emb, W, y, y_d, rne, rnw, psum, pkey, accum, (float*)d_out);
}